// Round 1
// baseline (4593.291 us; speedup 1.0000x reference)
//
#include <hip/hip_runtime.h>
#include <hip/hip_bf16.h>
#include <math.h>

// ---------------- problem constants ----------------
#define D        256
#define NINNER   2048
#define NROW     2049          // 2048 + dustbin
#define SP       2064          // padded row stride (floats), 16B-aligned rows
#define ITERS_N  100
#define EPS_F    0.8f
#define TAU_F    1.02f
#define NB       256           // persistent blocks
#define NT       256           // threads per block

// ws layout (in floats)
#define OFF_E    0u
#define SZ_MAT   (2049u * 2064u)          // 4229136
#define OFF_F    (OFF_E + SZ_MAT)
#define OFF_WU   (OFF_F + SZ_MAT)
#define OFF_WV   (OFF_WU + 2176u)
#define OFF_BAR  (OFF_WV + 2176u)         // 2048 uints
#define OFF_MAX0 (OFF_BAR + 2048u)
#define OFF_IDX0 (OFF_MAX0 + 2048u)
#define OFF_IDX1 (OFF_IDX0 + 2048u)
#define OFF_MS0  (OFF_IDX1 + 2048u)
#define OFF_VLD0 (OFF_MS0 + 2048u)

// d_out layout (floats)
#define OOFF_Z   0u
#define OOFF_I0  (2049u * 2049u)          // 4198401
#define OOFF_I1  (OOFF_I0 + 2048u)
#define OOFF_S0  (OOFF_I1 + 2048u)
#define OOFF_S1  (OOFF_S0 + 2048u)

// ---------------- K1: fp32 GEMM -> E = exp(scores) ----------------
// A = mdesc0 [d][i] (d*2048+i), B = mdesc1 [d][j]. E[i][j] = exp(dot/16).
__global__ __launch_bounds__(256) void k_gemm(const float* __restrict__ A,
                                              const float* __restrict__ Bm,
                                              float* __restrict__ E) {
    __shared__ float As[8][64];
    __shared__ float Bs[8][64];
    const int tid = threadIdx.x;
    const int tx = tid & 15, ty = tid >> 4;
    const int row0 = blockIdx.y * 64, col0 = blockIdx.x * 64;
    float acc[4][4] = {};
    const int lr = tid >> 6, lc = tid & 63;   // loader coords (4 rows x 64 cols x2)
    for (int k0 = 0; k0 < D; k0 += 8) {
        As[lr][lc]     = A[(k0 + lr) * NINNER + row0 + lc];
        As[lr + 4][lc] = A[(k0 + lr + 4) * NINNER + row0 + lc];
        Bs[lr][lc]     = Bm[(k0 + lr) * NINNER + col0 + lc];
        Bs[lr + 4][lc] = Bm[(k0 + lr + 4) * NINNER + col0 + lc];
        __syncthreads();
#pragma unroll
        for (int kk = 0; kk < 8; ++kk) {
            const float4 av = *(const float4*)&As[kk][ty * 4];
            const float4 bv = *(const float4*)&Bs[kk][tx * 4];
            const float a_[4] = {av.x, av.y, av.z, av.w};
            const float b_[4] = {bv.x, bv.y, bv.z, bv.w};
#pragma unroll
            for (int r = 0; r < 4; ++r)
#pragma unroll
                for (int c = 0; c < 4; ++c)
                    acc[r][c] = fmaf(a_[r], b_[c], acc[r][c]);
        }
        __syncthreads();
    }
    const int row = row0 + ty * 4, col = col0 + tx * 4;
#pragma unroll
    for (int r = 0; r < 4; ++r) {
        float4 o;
        o.x = expf(acc[r][0] * 0.0625f);
        o.y = expf(acc[r][1] * 0.0625f);
        o.z = expf(acc[r][2] * 0.0625f);
        o.w = expf(acc[r][3] * 0.0625f);
        *(float4*)(E + (size_t)(row + r) * SP + col) = o;
    }
}

// ---------------- K2a: bins, wv init, barrier init ----------------
__global__ __launch_bounds__(256) void k_init(float* __restrict__ E,
                                              float* __restrict__ wv,
                                              unsigned* __restrict__ bar,
                                              const float* __restrict__ alpha) {
    const int t = blockIdx.x * 256 + threadIdx.x;
    const float ea = expf(alpha[0]);
    if (t < NINNER) E[(size_t)t * SP + NINNER] = ea;        // bin column
    if (t <= NINNER) E[(size_t)NINNER * SP + t] = ea;       // bin row (+corner)
    if (t < 2176) wv[t] = (t <= NINNER) ? 1.0f : 0.0f;      // v0 = 0 -> wv = 1
    if (t < 2048) bar[t] = 0u;
}

// ---------------- K2b: F = E^T ----------------
__global__ __launch_bounds__(256) void k_transpose(const float* __restrict__ E,
                                                   float* __restrict__ F) {
    __shared__ float tle[32][33];
    const int tx = threadIdx.x & 31;
    const int ty4 = (threadIdx.x >> 5) * 4;
    const int bx = blockIdx.x * 32, by = blockIdx.y * 32;
#pragma unroll
    for (int k = 0; k < 4; ++k) {
        const int i = by + ty4 + k, j = bx + tx;
        if (i < NROW && j < NROW) tle[ty4 + k][tx] = E[(size_t)i * SP + j];
    }
    __syncthreads();
#pragma unroll
    for (int k = 0; k < 4; ++k) {
        const int j = bx + ty4 + k, i = by + tx;
        if (i < NROW && j < NROW) F[(size_t)j * SP + i] = tle[tx][ty4 + k];
    }
}

// ---------------- grid barrier (two-level 16x16 tree, atomics only) ----------------
__device__ __forceinline__ void grid_barrier(unsigned* bar, unsigned& epoch, int g) {
    __syncthreads();   // drains vmcnt: all prior agent-atomic stores at coherence point
    if (threadIdx.x == 0) {
        ++epoch;
        unsigned* grp  = bar + (2 + g) * 64;
        unsigned* root = bar;
        unsigned* gen  = bar + 64;
        bool done = false;
        unsigned p = __hip_atomic_fetch_add(grp, 1u, __ATOMIC_ACQ_REL, __HIP_MEMORY_SCOPE_AGENT);
        if (p == 15u) {
            unsigned q = __hip_atomic_fetch_add(root, 1u, __ATOMIC_ACQ_REL, __HIP_MEMORY_SCOPE_AGENT);
            if (q == 15u) {
#pragma unroll
                for (int k = 0; k < 16; ++k)
                    __hip_atomic_store(bar + (2 + k) * 64, 0u, __ATOMIC_RELAXED, __HIP_MEMORY_SCOPE_AGENT);
                __hip_atomic_store(root, 0u, __ATOMIC_RELAXED, __HIP_MEMORY_SCOPE_AGENT);
                __hip_atomic_store(gen, epoch, __ATOMIC_RELEASE, __HIP_MEMORY_SCOPE_AGENT);
                done = true;
            }
        }
        if (!done) {
            while (__hip_atomic_load(gen, __ATOMIC_ACQUIRE, __HIP_MEMORY_SCOPE_AGENT) < epoch)
                __builtin_amdgcn_s_sleep(1);
        }
    }
    __syncthreads();
}

// ---------------- K3: persistent Sinkhorn ----------------
// Block b owns rows [8b,8b+8) of E and cols [8b,8b+8) of F (block 255 gets 9 incl. dustbin).
// Matrix fragments live in registers across all 100 iterations; only wu/wv move (agent atomics).
__global__ __launch_bounds__(256, 1) void k_sinkhorn(const float* __restrict__ E,
                                                     const float* __restrict__ F,
                                                     float* wu, float* wv,
                                                     unsigned* bar) {
    const int b = blockIdx.x, tid = threadIdx.x;
    const int lane = tid & 63, wid = tid >> 6;
    const int base = b * 8;
    const int nr = (b == NB - 1) ? 9 : 8;
    const int g = b >> 4;
    __shared__ float red[4][9];

    const float norm = -8.317766166719343f;            // -log(4096)
    const float logbin = logf(2048.0f) + norm;          // log(n) + norm

    // register-resident matrix fragments
    float4 er[9][2], fr[9][2];
    float ebin[9], fbin[9];
    for (int r = 0; r < nr; ++r) {
        const float* rowE = E + (size_t)(base + r) * SP;
        const float* rowF = F + (size_t)(base + r) * SP;
        er[r][0] = *(const float4*)(rowE + tid * 8);
        er[r][1] = *(const float4*)(rowE + tid * 8 + 4);
        fr[r][0] = *(const float4*)(rowF + tid * 8);
        fr[r][1] = *(const float4*)(rowF + tid * 8 + 4);
        ebin[r] = (tid == 0) ? rowE[NINNER] : 0.0f;
        fbin[r] = (tid == 0) ? rowF[NINNER] : 0.0f;
    }

    float u = 0.0f, v = 0.0f;
    unsigned epoch = 0;
    float p[9];

    for (int it = 0; it < ITERS_N; ++it) {
        // ---- phase A: row lse with wv -> update u, publish wu ----
        {
            float w[8];
#pragma unroll
            for (int q = 0; q < 8; ++q)
                w[q] = __hip_atomic_load(wv + tid * 8 + q, __ATOMIC_RELAXED, __HIP_MEMORY_SCOPE_AGENT);
            float wb = (tid == 0)
                ? __hip_atomic_load(wv + NINNER, __ATOMIC_RELAXED, __HIP_MEMORY_SCOPE_AGENT) : 0.0f;
            for (int r = 0; r < nr; ++r) {
                const float4 a = er[r][0], c = er[r][1];
                float s = a.x * w[0] + a.y * w[1] + a.z * w[2] + a.w * w[3]
                        + c.x * w[4] + c.y * w[5] + c.z * w[6] + c.w * w[7];
                if (tid == 0) s += ebin[r] * wb;
                p[r] = s;
            }
            for (int r = 0; r < nr; ++r) {
                float s = p[r];
#pragma unroll
                for (int m = 1; m < 64; m <<= 1) s += __shfl_xor(s, m, 64);
                if (lane == 0) red[wid][r] = s;
            }
            __syncthreads();
            if (tid < nr) {
                const float S = red[0][tid] + red[1][tid] + red[2][tid] + red[3][tid];
                const float lmu = (base + tid == NINNER) ? logbin : norm;
                const float unew = (lmu - logf(S)) / TAU_F;
                u = u + EPS_F * (unew - u);
                __hip_atomic_store(wu + base + tid, expf(u), __ATOMIC_RELAXED, __HIP_MEMORY_SCOPE_AGENT);
            }
        }
        grid_barrier(bar, epoch, g);
        // ---- phase B: col lse with wu -> update v, publish wv ----
        {
            float w[8];
#pragma unroll
            for (int q = 0; q < 8; ++q)
                w[q] = __hip_atomic_load(wu + tid * 8 + q, __ATOMIC_RELAXED, __HIP_MEMORY_SCOPE_AGENT);
            float wb = (tid == 0)
                ? __hip_atomic_load(wu + NINNER, __ATOMIC_RELAXED, __HIP_MEMORY_SCOPE_AGENT) : 0.0f;
            for (int r = 0; r < nr; ++r) {
                const float4 a = fr[r][0], c = fr[r][1];
                float s = a.x * w[0] + a.y * w[1] + a.z * w[2] + a.w * w[3]
                        + c.x * w[4] + c.y * w[5] + c.z * w[6] + c.w * w[7];
                if (tid == 0) s += fbin[r] * wb;
                p[r] = s;
            }
            for (int r = 0; r < nr; ++r) {
                float s = p[r];
#pragma unroll
                for (int m = 1; m < 64; m <<= 1) s += __shfl_xor(s, m, 64);
                if (lane == 0) red[wid][r] = s;
            }
            __syncthreads();
            if (tid < nr) {
                const float T = red[0][tid] + red[1][tid] + red[2][tid] + red[3][tid];
                const float lnu = (base + tid == NINNER) ? logbin : norm;
                const float vnew = (lnu - logf(T)) / TAU_F;
                v = v + EPS_F * (vnew - v);
                __hip_atomic_store(wv + base + tid, expf(v), __ATOMIC_RELAXED, __HIP_MEMORY_SCOPE_AGENT);
            }
        }
        grid_barrier(bar, epoch, g);
    }
}

// ---------------- K4: out0 = exp(Z) + row max/argmax ----------------
__global__ __launch_bounds__(256) void k_rowpass(const float* __restrict__ E,
                                                 const float* __restrict__ wu,
                                                 const float* __restrict__ wv,
                                                 float* __restrict__ out,
                                                 float* __restrict__ max0,
                                                 int* __restrict__ idx0) {
    const int i = blockIdx.x;                 // 0..2048
    const int tid = threadIdx.x;
    const int lane = tid & 63, wid = tid >> 6;
    const float wui = wu[i] * 4096.0f;        // * exp(-norm)
    const float* row = E + (size_t)i * SP;
    float best = -1.0f; int bidx = 0;
    for (int j = tid; j < NROW; j += 256) {
        const float val = row[j] * wv[j] * wui;
        out[(size_t)i * NROW + j] = val;
        if (j < NINNER && val > best) { best = val; bidx = j; }
    }
    if (i < NINNER) {
        __shared__ float sb[4]; __shared__ int si[4];
#pragma unroll
        for (int m = 1; m < 64; m <<= 1) {
            const float ob = __shfl_xor(best, m, 64);
            const int   oi = __shfl_xor(bidx, m, 64);
            if (ob > best || (ob == best && oi < bidx)) { best = ob; bidx = oi; }
        }
        if (lane == 0) { sb[wid] = best; si[wid] = bidx; }
        __syncthreads();
        if (tid == 0) {
            for (int k = 1; k < 4; ++k)
                if (sb[k] > best || (sb[k] == best && si[k] < bidx)) { best = sb[k]; bidx = si[k]; }
            max0[i] = best; idx0[i] = bidx;
        }
    }
}

// ---------------- K5: col argmax via F ----------------
__global__ __launch_bounds__(256) void k_colpass(const float* __restrict__ F,
                                                 const float* __restrict__ wu,
                                                 int* __restrict__ idx1) {
    const int j = blockIdx.x;                 // 0..2047
    const int tid = threadIdx.x;
    const int lane = tid & 63, wid = tid >> 6;
    const float* row = F + (size_t)j * SP;
    float best = -1.0f; int bidx = 0;
    for (int i = tid; i < NINNER; i += 256) {
        const float q = row[i] * wu[i];
        if (q > best) { best = q; bidx = i; }
    }
    __shared__ float sb[4]; __shared__ int si[4];
#pragma unroll
    for (int m = 1; m < 64; m <<= 1) {
        const float ob = __shfl_xor(best, m, 64);
        const int   oi = __shfl_xor(bidx, m, 64);
        if (ob > best || (ob == best && oi < bidx)) { best = ob; bidx = oi; }
    }
    if (lane == 0) { sb[wid] = best; si[wid] = bidx; }
    __syncthreads();
    if (tid == 0) {
        for (int k = 1; k < 4; ++k)
            if (sb[k] > best || (sb[k] == best && si[k] < bidx)) { best = sb[k]; bidx = si[k]; }
        idx1[j] = bidx;
    }
}

// ---------------- K6a/K6b: mutual matching ----------------
__global__ __launch_bounds__(256) void k_match0(const float* __restrict__ max0,
                                                const int* __restrict__ idx0,
                                                const int* __restrict__ idx1,
                                                float* __restrict__ ms0,
                                                int* __restrict__ vld0,
                                                float* __restrict__ out) {
    const int i = blockIdx.x * 256 + threadIdx.x;
    if (i >= NINNER) return;
    const int j = idx0[i];
    const bool mut = (idx1[j] == i);
    const float ms = mut ? max0[i] : 0.0f;
    const bool val = mut && (ms > 0.2f);
    ms0[i] = ms; vld0[i] = val ? 1 : 0;
    out[OOFF_I0 + i] = val ? (float)j : -1.0f;
    out[OOFF_S0 + i] = ms;
}
__global__ __launch_bounds__(256) void k_match1(const int* __restrict__ idx0,
                                                const int* __restrict__ idx1,
                                                const float* __restrict__ ms0,
                                                const int* __restrict__ vld0,
                                                float* __restrict__ out) {
    const int j = blockIdx.x * 256 + threadIdx.x;
    if (j >= NINNER) return;
    const int i = idx1[j];
    const bool mut = (idx0[i] == j);
    const float ms = mut ? ms0[i] : 0.0f;
    const bool val = mut && (vld0[i] != 0);
    out[OOFF_I1 + j] = val ? (float)i : -1.0f;
    out[OOFF_S1 + j] = ms;
}

// ---------------- host ----------------
extern "C" void kernel_launch(void* const* d_in, const int* in_sizes, int n_in,
                              void* d_out, int out_size, void* d_ws, size_t ws_size,
                              hipStream_t stream) {
    const float* A     = (const float*)d_in[0];   // mdesc0 (1,256,2048)
    const float* Bm    = (const float*)d_in[1];   // mdesc1 (1,256,2048)
    const float* alpha = (const float*)d_in[2];   // bin_score scalar

    float* ws = (float*)d_ws;
    float*    E    = ws + OFF_E;
    float*    F    = ws + OFF_F;
    float*    wu   = ws + OFF_WU;
    float*    wv   = ws + OFF_WV;
    unsigned* bar  = (unsigned*)(ws + OFF_BAR);
    float*    max0 = ws + OFF_MAX0;
    int*      idx0 = (int*)(ws + OFF_IDX0);
    int*      idx1 = (int*)(ws + OFF_IDX1);
    float*    ms0  = ws + OFF_MS0;
    int*      vld0 = (int*)(ws + OFF_VLD0);
    float*    out  = (float*)d_out;

    k_gemm<<<dim3(32, 32), 256, 0, stream>>>(A, Bm, E);
    k_init<<<dim3(9), 256, 0, stream>>>(E, wv, bar, alpha);
    k_transpose<<<dim3(65, 65), 256, 0, stream>>>(E, F);
    k_sinkhorn<<<dim3(NB), NT, 0, stream>>>(E, F, wu, wv, bar);
    k_rowpass<<<dim3(NROW), 256, 0, stream>>>(E, wu, wv, out, max0, idx0);
    k_colpass<<<dim3(NINNER), 256, 0, stream>>>(F, wu, idx1);
    k_match0<<<dim3(8), 256, 0, stream>>>(max0, idx0, idx1, ms0, vld0, out);
    k_match1<<<dim3(8), 256, 0, stream>>>(idx0, idx1, ms0, vld0, out);
}

// Round 2
// 4009.154 us; speedup vs baseline: 1.1457x; 1.1457x over previous
//
#include <hip/hip_runtime.h>
#include <hip/hip_bf16.h>
#include <math.h>

// ---------------- problem constants ----------------
#define D        256
#define NINNER   2048
#define NROW     2049          // 2048 + dustbin
#define SP       2064          // padded row stride (floats), 16B-aligned rows
#define ITERS_N  100
#define EPS_F    0.8f
#define TAU_F    1.02f
#define NB       256           // persistent blocks
#define NT       256           // threads per block

// ws layout (in floats)
#define OFF_E    0u
#define SZ_MAT   (2049u * 2064u)          // 4229136
#define OFF_F    (OFF_E + SZ_MAT)
#define OFF_WU   (OFF_F + SZ_MAT)
#define OFF_WV   (OFF_WU + 2176u)
#define OFF_BAR  (OFF_WV + 2176u)         // 2048 uints
#define OFF_MAX0 (OFF_BAR + 2048u)
#define OFF_IDX0 (OFF_MAX0 + 2048u)
#define OFF_IDX1 (OFF_IDX0 + 2048u)
#define OFF_MS0  (OFF_IDX1 + 2048u)
#define OFF_VLD0 (OFF_MS0 + 2048u)

// d_out layout (floats)
#define OOFF_Z   0u
#define OOFF_I0  (2049u * 2049u)          // 4198401
#define OOFF_I1  (OOFF_I0 + 2048u)
#define OOFF_S0  (OOFF_I1 + 2048u)
#define OOFF_S1  (OOFF_S0 + 2048u)

// ---------------- K1: fp32 GEMM -> E = exp(scores) ----------------
__global__ __launch_bounds__(256) void k_gemm(const float* __restrict__ A,
                                              const float* __restrict__ Bm,
                                              float* __restrict__ E) {
    __shared__ float As[8][64];
    __shared__ float Bs[8][64];
    const int tid = threadIdx.x;
    const int tx = tid & 15, ty = tid >> 4;
    const int row0 = blockIdx.y * 64, col0 = blockIdx.x * 64;
    float acc[4][4] = {};
    const int lr = tid >> 6, lc = tid & 63;
    for (int k0 = 0; k0 < D; k0 += 8) {
        As[lr][lc]     = A[(k0 + lr) * NINNER + row0 + lc];
        As[lr + 4][lc] = A[(k0 + lr + 4) * NINNER + row0 + lc];
        Bs[lr][lc]     = Bm[(k0 + lr) * NINNER + col0 + lc];
        Bs[lr + 4][lc] = Bm[(k0 + lr + 4) * NINNER + col0 + lc];
        __syncthreads();
#pragma unroll
        for (int kk = 0; kk < 8; ++kk) {
            const float4 av = *(const float4*)&As[kk][ty * 4];
            const float4 bv = *(const float4*)&Bs[kk][tx * 4];
            const float a_[4] = {av.x, av.y, av.z, av.w};
            const float b_[4] = {bv.x, bv.y, bv.z, bv.w};
#pragma unroll
            for (int r = 0; r < 4; ++r)
#pragma unroll
                for (int c = 0; c < 4; ++c)
                    acc[r][c] = fmaf(a_[r], b_[c], acc[r][c]);
        }
        __syncthreads();
    }
    const int row = row0 + ty * 4, col = col0 + tx * 4;
#pragma unroll
    for (int r = 0; r < 4; ++r) {
        float4 o;
        o.x = expf(acc[r][0] * 0.0625f);
        o.y = expf(acc[r][1] * 0.0625f);
        o.z = expf(acc[r][2] * 0.0625f);
        o.w = expf(acc[r][3] * 0.0625f);
        *(float4*)(E + (size_t)(row + r) * SP + col) = o;
    }
}

// ---------------- K2a: bins, wv init, barrier init ----------------
__global__ __launch_bounds__(256) void k_init(float* __restrict__ E,
                                              float* __restrict__ wv,
                                              unsigned* __restrict__ bar,
                                              const float* __restrict__ alpha) {
    const int t = blockIdx.x * 256 + threadIdx.x;
    const float ea = expf(alpha[0]);
    if (t < NINNER) E[(size_t)t * SP + NINNER] = ea;        // bin column
    if (t <= NINNER) E[(size_t)NINNER * SP + t] = ea;       // bin row (+corner)
    if (t < 2176) wv[t] = (t <= NINNER) ? 1.0f : 0.0f;      // v0 = 0 -> wv = 1
    if (t < 2048) bar[t] = 0u;
}

// ---------------- K2b: F = E^T ----------------
__global__ __launch_bounds__(256) void k_transpose(const float* __restrict__ E,
                                                   float* __restrict__ F) {
    __shared__ float tle[32][33];
    const int tx = threadIdx.x & 31;
    const int ty4 = (threadIdx.x >> 5) * 4;
    const int bx = blockIdx.x * 32, by = blockIdx.y * 32;
#pragma unroll
    for (int k = 0; k < 4; ++k) {
        const int i = by + ty4 + k, j = bx + tx;
        if (i < NROW && j < NROW) tle[ty4 + k][tx] = E[(size_t)i * SP + j];
    }
    __syncthreads();
#pragma unroll
    for (int k = 0; k < 4; ++k) {
        const int j = bx + ty4 + k, i = by + tx;
        if (i < NROW && j < NROW) F[(size_t)j * SP + i] = tle[tx][ty4 + k];
    }
}

// ---------------- grid barrier (two-level 16x16 tree, atomics only) ----------------
__device__ __forceinline__ void grid_barrier(unsigned* bar, unsigned& epoch, int g) {
    __syncthreads();
    if (threadIdx.x == 0) {
        ++epoch;
        unsigned* grp  = bar + (2 + g) * 64;
        unsigned* root = bar;
        unsigned* gen  = bar + 64;
        bool done = false;
        unsigned p = __hip_atomic_fetch_add(grp, 1u, __ATOMIC_ACQ_REL, __HIP_MEMORY_SCOPE_AGENT);
        if (p == 15u) {
            unsigned q = __hip_atomic_fetch_add(root, 1u, __ATOMIC_ACQ_REL, __HIP_MEMORY_SCOPE_AGENT);
            if (q == 15u) {
#pragma unroll
                for (int k = 0; k < 16; ++k)
                    __hip_atomic_store(bar + (2 + k) * 64, 0u, __ATOMIC_RELAXED, __HIP_MEMORY_SCOPE_AGENT);
                __hip_atomic_store(root, 0u, __ATOMIC_RELAXED, __HIP_MEMORY_SCOPE_AGENT);
                __hip_atomic_store(gen, epoch, __ATOMIC_RELEASE, __HIP_MEMORY_SCOPE_AGENT);
                done = true;
            }
        }
        if (!done) {
            while (__hip_atomic_load(gen, __ATOMIC_ACQUIRE, __HIP_MEMORY_SCOPE_AGENT) < epoch)
                __builtin_amdgcn_s_sleep(1);
        }
    }
    __syncthreads();
}

// ---------------- K3: persistent Sinkhorn ----------------
// Block b owns rows [8b,8b+8) of E and cols [8b,8b+8) of F — ALL loops have
// compile-time bounds so er/fr stay in VGPRs (round-1 failure: runtime bound
// nr -> dynamic indexing -> scratch spill -> 740 MB HBM/iter-set).
// Dustbin row/col are constant exp(alpha): logsumexp = ea * sum(wv)  — computed
// analytically from the full wv each block already reads (virtual "row 8").
__global__ __launch_bounds__(256, 1) void k_sinkhorn(const float* __restrict__ E,
                                                     const float* __restrict__ F,
                                                     float* wu, float* wv,
                                                     unsigned* bar,
                                                     const float* __restrict__ alpha) {
    const int b = blockIdx.x, tid = threadIdx.x;
    const int lane = tid & 63, wid = tid >> 6;
    const int base = b * 8;
    const bool last = (b == NB - 1);
    const int g = b >> 4;
    __shared__ float red[4][9];

    const float norm = -8.317766166719343f;            // -log(4096)
    const float logbin = 7.624618986159398f + norm;     // log(2048) + norm
    const float ea = expf(alpha[0]);

    // register-resident matrix fragments (constant indexing only!)
    float4 er[8][2], fr[8][2];
#pragma unroll
    for (int r = 0; r < 8; ++r) {
        const float* rowE = E + (size_t)(base + r) * SP;
        const float* rowF = F + (size_t)(base + r) * SP;
        er[r][0] = *(const float4*)(rowE + tid * 8);
        er[r][1] = *(const float4*)(rowE + tid * 8 + 4);
        fr[r][0] = *(const float4*)(rowF + tid * 8);
        fr[r][1] = *(const float4*)(rowF + tid * 8 + 4);
    }

    float u = 0.0f, v = 0.0f;      // potential for row/col (base+tid), tid<8
    float ub = 0.0f, vb = 0.0f;    // dustbin potentials (block 255, tid 8)
    unsigned epoch = 0;

    for (int it = 0; it < ITERS_N; ++it) {
        // ---- phase A: S_i = sum_j E_ij wv_j -> update u, publish wu ----
        {
            float w[8];
#pragma unroll
            for (int q = 0; q < 8; ++q)
                w[q] = __hip_atomic_load(wv + tid * 8 + q, __ATOMIC_RELAXED, __HIP_MEMORY_SCOPE_AGENT);
            const float wb = (tid == 0)
                ? __hip_atomic_load(wv + NINNER, __ATOMIC_RELAXED, __HIP_MEMORY_SCOPE_AGENT) : 0.0f;
            float p[8];
#pragma unroll
            for (int r = 0; r < 8; ++r) {
                const float4 a = er[r][0], c = er[r][1];
                p[r] = a.x * w[0] + a.y * w[1] + a.z * w[2] + a.w * w[3]
                     + c.x * w[4] + c.y * w[5] + c.z * w[6] + c.w * w[7]
                     + ea * wb;                         // wb==0 except tid 0
            }
            float t = w[0] + w[1] + w[2] + w[3] + w[4] + w[5] + w[6] + w[7] + wb;
#pragma unroll
            for (int r = 0; r < 8; ++r) {
                float s = p[r];
#pragma unroll
                for (int m = 1; m < 64; m <<= 1) s += __shfl_xor(s, m, 64);
                if (lane == 0) red[wid][r] = s;
            }
#pragma unroll
            for (int m = 1; m < 64; m <<= 1) t += __shfl_xor(t, m, 64);
            if (lane == 0) red[wid][8] = t;
            __syncthreads();
            if (tid < 8) {
                const float S = red[0][tid] + red[1][tid] + red[2][tid] + red[3][tid];
                const float unew = (norm - logf(S)) / TAU_F;
                u = u + EPS_F * (unew - u);
                __hip_atomic_store(wu + base + tid, expf(u), __ATOMIC_RELAXED, __HIP_MEMORY_SCOPE_AGENT);
            }
            if (last && tid == 8) {
                const float S = ea * (red[0][8] + red[1][8] + red[2][8] + red[3][8]);
                const float unew = (logbin - logf(S)) / TAU_F;
                ub = ub + EPS_F * (unew - ub);
                __hip_atomic_store(wu + NINNER, expf(ub), __ATOMIC_RELAXED, __HIP_MEMORY_SCOPE_AGENT);
            }
        }
        grid_barrier(bar, epoch, g);
        // ---- phase B: T_j = sum_i F_ji wu_i -> update v, publish wv ----
        {
            float w[8];
#pragma unroll
            for (int q = 0; q < 8; ++q)
                w[q] = __hip_atomic_load(wu + tid * 8 + q, __ATOMIC_RELAXED, __HIP_MEMORY_SCOPE_AGENT);
            const float wb = (tid == 0)
                ? __hip_atomic_load(wu + NINNER, __ATOMIC_RELAXED, __HIP_MEMORY_SCOPE_AGENT) : 0.0f;
            float p[8];
#pragma unroll
            for (int r = 0; r < 8; ++r) {
                const float4 a = fr[r][0], c = fr[r][1];
                p[r] = a.x * w[0] + a.y * w[1] + a.z * w[2] + a.w * w[3]
                     + c.x * w[4] + c.y * w[5] + c.z * w[6] + c.w * w[7]
                     + ea * wb;
            }
            float t = w[0] + w[1] + w[2] + w[3] + w[4] + w[5] + w[6] + w[7] + wb;
#pragma unroll
            for (int r = 0; r < 8; ++r) {
                float s = p[r];
#pragma unroll
                for (int m = 1; m < 64; m <<= 1) s += __shfl_xor(s, m, 64);
                if (lane == 0) red[wid][r] = s;
            }
#pragma unroll
            for (int m = 1; m < 64; m <<= 1) t += __shfl_xor(t, m, 64);
            if (lane == 0) red[wid][8] = t;
            __syncthreads();
            if (tid < 8) {
                const float T = red[0][tid] + red[1][tid] + red[2][tid] + red[3][tid];
                const float vnew = (norm - logf(T)) / TAU_F;
                v = v + EPS_F * (vnew - v);
                __hip_atomic_store(wv + base + tid, expf(v), __ATOMIC_RELAXED, __HIP_MEMORY_SCOPE_AGENT);
            }
            if (last && tid == 8) {
                const float T = ea * (red[0][8] + red[1][8] + red[2][8] + red[3][8]);
                const float vnew = (logbin - logf(T)) / TAU_F;
                vb = vb + EPS_F * (vnew - vb);
                __hip_atomic_store(wv + NINNER, expf(vb), __ATOMIC_RELAXED, __HIP_MEMORY_SCOPE_AGENT);
            }
        }
        grid_barrier(bar, epoch, g);
    }
}

// ---------------- K4: out0 = exp(Z) + row max/argmax ----------------
__global__ __launch_bounds__(256) void k_rowpass(const float* __restrict__ E,
                                                 const float* __restrict__ wu,
                                                 const float* __restrict__ wv,
                                                 float* __restrict__ out,
                                                 float* __restrict__ max0,
                                                 int* __restrict__ idx0) {
    const int i = blockIdx.x;                 // 0..2048
    const int tid = threadIdx.x;
    const int lane = tid & 63, wid = tid >> 6;
    const float wui = wu[i] * 4096.0f;        // * exp(-norm)
    const float* row = E + (size_t)i * SP;
    float best = -1.0f; int bidx = 0;
    for (int j = tid; j < NROW; j += 256) {
        const float val = row[j] * wv[j] * wui;
        out[(size_t)i * NROW + j] = val;
        if (j < NINNER && val > best) { best = val; bidx = j; }
    }
    if (i < NINNER) {
        __shared__ float sb[4]; __shared__ int si[4];
#pragma unroll
        for (int m = 1; m < 64; m <<= 1) {
            const float ob = __shfl_xor(best, m, 64);
            const int   oi = __shfl_xor(bidx, m, 64);
            if (ob > best || (ob == best && oi < bidx)) { best = ob; bidx = oi; }
        }
        if (lane == 0) { sb[wid] = best; si[wid] = bidx; }
        __syncthreads();
        if (tid == 0) {
            for (int k = 1; k < 4; ++k)
                if (sb[k] > best || (sb[k] == best && si[k] < bidx)) { best = sb[k]; bidx = si[k]; }
            max0[i] = best; idx0[i] = bidx;
        }
    }
}

// ---------------- K5: col argmax via F ----------------
__global__ __launch_bounds__(256) void k_colpass(const float* __restrict__ F,
                                                 const float* __restrict__ wu,
                                                 int* __restrict__ idx1) {
    const int j = blockIdx.x;                 // 0..2047
    const int tid = threadIdx.x;
    const int lane = tid & 63, wid = tid >> 6;
    const float* row = F + (size_t)j * SP;
    float best = -1.0f; int bidx = 0;
    for (int i = tid; i < NINNER; i += 256) {
        const float q = row[i] * wu[i];
        if (q > best) { best = q; bidx = i; }
    }
    __shared__ float sb[4]; __shared__ int si[4];
#pragma unroll
    for (int m = 1; m < 64; m <<= 1) {
        const float ob = __shfl_xor(best, m, 64);
        const int   oi = __shfl_xor(bidx, m, 64);
        if (ob > best || (ob == best && oi < bidx)) { best = ob; bidx = oi; }
    }
    if (lane == 0) { sb[wid] = best; si[wid] = bidx; }
    __syncthreads();
    if (tid == 0) {
        for (int k = 1; k < 4; ++k)
            if (sb[k] > best || (sb[k] == best && si[k] < bidx)) { best = sb[k]; bidx = si[k]; }
        idx1[j] = bidx;
    }
}

// ---------------- K6a/K6b: mutual matching ----------------
__global__ __launch_bounds__(256) void k_match0(const float* __restrict__ max0,
                                                const int* __restrict__ idx0,
                                                const int* __restrict__ idx1,
                                                float* __restrict__ ms0,
                                                int* __restrict__ vld0,
                                                float* __restrict__ out) {
    const int i = blockIdx.x * 256 + threadIdx.x;
    if (i >= NINNER) return;
    const int j = idx0[i];
    const bool mut = (idx1[j] == i);
    const float ms = mut ? max0[i] : 0.0f;
    const bool val = mut && (ms > 0.2f);
    ms0[i] = ms; vld0[i] = val ? 1 : 0;
    out[OOFF_I0 + i] = val ? (float)j : -1.0f;
    out[OOFF_S0 + i] = ms;
}
__global__ __launch_bounds__(256) void k_match1(const int* __restrict__ idx0,
                                                const int* __restrict__ idx1,
                                                const float* __restrict__ ms0,
                                                const int* __restrict__ vld0,
                                                float* __restrict__ out) {
    const int j = blockIdx.x * 256 + threadIdx.x;
    if (j >= NINNER) return;
    const int i = idx1[j];
    const bool mut = (idx0[i] == j);
    const float ms = mut ? ms0[i] : 0.0f;
    const bool val = mut && (vld0[i] != 0);
    out[OOFF_I1 + j] = val ? (float)i : -1.0f;
    out[OOFF_S1 + j] = ms;
}

// ---------------- host ----------------
extern "C" void kernel_launch(void* const* d_in, const int* in_sizes, int n_in,
                              void* d_out, int out_size, void* d_ws, size_t ws_size,
                              hipStream_t stream) {
    const float* A     = (const float*)d_in[0];   // mdesc0 (1,256,2048)
    const float* Bm    = (const float*)d_in[1];   // mdesc1 (1,256,2048)
    const float* alpha = (const float*)d_in[2];   // bin_score scalar

    float* ws = (float*)d_ws;
    float*    E    = ws + OFF_E;
    float*    F    = ws + OFF_F;
    float*    wu   = ws + OFF_WU;
    float*    wv   = ws + OFF_WV;
    unsigned* bar  = (unsigned*)(ws + OFF_BAR);
    float*    max0 = ws + OFF_MAX0;
    int*      idx0 = (int*)(ws + OFF_IDX0);
    int*      idx1 = (int*)(ws + OFF_IDX1);
    float*    ms0  = ws + OFF_MS0;
    int*      vld0 = (int*)(ws + OFF_VLD0);
    float*    out  = (float*)d_out;

    k_gemm<<<dim3(32, 32), 256, 0, stream>>>(A, Bm, E);
    k_init<<<dim3(9), 256, 0, stream>>>(E, wv, bar, alpha);
    k_transpose<<<dim3(65, 65), 256, 0, stream>>>(E, F);
    k_sinkhorn<<<dim3(NB), NT, 0, stream>>>(E, F, wu, wv, bar, alpha);
    k_rowpass<<<dim3(NROW), 256, 0, stream>>>(E, wu, wv, out, max0, idx0);
    k_colpass<<<dim3(NINNER), 256, 0, stream>>>(F, wu, idx1);
    k_match0<<<dim3(8), 256, 0, stream>>>(max0, idx0, idx1, ms0, vld0, out);
    k_match1<<<dim3(8), 256, 0, stream>>>(idx0, idx1, ms0, vld0, out);
}

// Round 3
// 1598.702 us; speedup vs baseline: 2.8731x; 2.5078x over previous
//
#include <hip/hip_runtime.h>
#include <hip/hip_bf16.h>
#include <math.h>

// ---------------- problem constants ----------------
#define D        256
#define NINNER   2048
#define NROW     2049          // 2048 + dustbin
#define SP       2064          // padded row stride (floats), 16B-aligned rows
#define ITERS_N  100
#define EPS_F    0.8f
#define TAU_F    1.02f
#define NB       256           // persistent blocks
#define NT       256           // threads per block

// ws layout (in floats)
#define OFF_E    0u
#define SZ_MAT   (2049u * 2064u)          // 4229136
#define OFF_F    (OFF_E + SZ_MAT)
#define OFF_WU   (OFF_F + SZ_MAT)
#define OFF_WV   (OFF_WU + 2176u)
#define OFF_BAR  (OFF_WV + 2176u)         // 4096 uints (33 x 64-uint lines used)
#define OFF_MAX0 (OFF_BAR + 4096u)
#define OFF_IDX0 (OFF_MAX0 + 2048u)
#define OFF_IDX1 (OFF_IDX0 + 2048u)
#define OFF_MS0  (OFF_IDX1 + 2048u)
#define OFF_VLD0 (OFF_MS0 + 2048u)

// d_out layout (floats)
#define OOFF_Z   0u
#define OOFF_I0  (2049u * 2049u)          // 4198401
#define OOFF_I1  (OOFF_I0 + 2048u)
#define OOFF_S0  (OOFF_I1 + 2048u)
#define OOFF_S1  (OOFF_S0 + 2048u)

// bar layout (uint32 units, 64-uint = 256B line stride):
//   bar[0]            root counter
//   bar[64*(1+g)]     gen broadcast line for group g   (g = 0..15)
//   bar[64*(17+g)]    arrival counter for group g

// ---------------- K1: fp32 GEMM -> E = exp(scores) ----------------
__global__ __launch_bounds__(256) void k_gemm(const float* __restrict__ A,
                                              const float* __restrict__ Bm,
                                              float* __restrict__ E) {
    __shared__ float As[8][64];
    __shared__ float Bs[8][64];
    const int tid = threadIdx.x;
    const int tx = tid & 15, ty = tid >> 4;
    const int row0 = blockIdx.y * 64, col0 = blockIdx.x * 64;
    float acc[4][4] = {};
    const int lr = tid >> 6, lc = tid & 63;
    for (int k0 = 0; k0 < D; k0 += 8) {
        As[lr][lc]     = A[(k0 + lr) * NINNER + row0 + lc];
        As[lr + 4][lc] = A[(k0 + lr + 4) * NINNER + row0 + lc];
        Bs[lr][lc]     = Bm[(k0 + lr) * NINNER + col0 + lc];
        Bs[lr + 4][lc] = Bm[(k0 + lr + 4) * NINNER + col0 + lc];
        __syncthreads();
#pragma unroll
        for (int kk = 0; kk < 8; ++kk) {
            const float4 av = *(const float4*)&As[kk][ty * 4];
            const float4 bv = *(const float4*)&Bs[kk][tx * 4];
            const float a_[4] = {av.x, av.y, av.z, av.w};
            const float b_[4] = {bv.x, bv.y, bv.z, bv.w};
#pragma unroll
            for (int r = 0; r < 4; ++r)
#pragma unroll
                for (int c = 0; c < 4; ++c)
                    acc[r][c] = fmaf(a_[r], b_[c], acc[r][c]);
        }
        __syncthreads();
    }
    const int row = row0 + ty * 4, col = col0 + tx * 4;
#pragma unroll
    for (int r = 0; r < 4; ++r) {
        float4 o;
        o.x = expf(acc[r][0] * 0.0625f);
        o.y = expf(acc[r][1] * 0.0625f);
        o.z = expf(acc[r][2] * 0.0625f);
        o.w = expf(acc[r][3] * 0.0625f);
        *(float4*)(E + (size_t)(row + r) * SP + col) = o;
    }
}

// ---------------- K2a: bins, wv init, barrier init ----------------
__global__ __launch_bounds__(256) void k_init(float* __restrict__ E,
                                              float* __restrict__ wv,
                                              unsigned* __restrict__ bar,
                                              const float* __restrict__ alpha) {
    const int t = blockIdx.x * 256 + threadIdx.x;
    const float ea = expf(alpha[0]);
    if (t < NINNER) E[(size_t)t * SP + NINNER] = ea;        // bin column
    if (t <= NINNER) E[(size_t)NINNER * SP + t] = ea;       // bin row (+corner)
    if (t < 2176) wv[t] = (t <= NINNER) ? 1.0f : 0.0f;      // v0 = 0 -> wv = 1
    if (t < 4096) bar[t] = 0u;
}

// ---------------- K2b: F = E^T ----------------
__global__ __launch_bounds__(256) void k_transpose(const float* __restrict__ E,
                                                   float* __restrict__ F) {
    __shared__ float tle[32][33];
    const int tx = threadIdx.x & 31;
    const int ty4 = (threadIdx.x >> 5) * 4;
    const int bx = blockIdx.x * 32, by = blockIdx.y * 32;
#pragma unroll
    for (int k = 0; k < 4; ++k) {
        const int i = by + ty4 + k, j = bx + tx;
        if (i < NROW && j < NROW) tle[ty4 + k][tx] = E[(size_t)i * SP + j];
    }
    __syncthreads();
#pragma unroll
    for (int k = 0; k < 4; ++k) {
        const int j = bx + ty4 + k, i = by + tx;
        if (i < NROW && j < NROW) F[(size_t)j * SP + i] = tle[tx][ty4 + k];
    }
}

// ---------------- grid barrier: relaxed flags + hoisted fences ----------------
// Arrival/poll atomics are RELAXED (no per-op cache-ops). Ordering:
//   producer: data stores -> release fence (drains) -> relaxed arrival add
//   consumer: relaxed poll observes gen -> acquire fence (inv L1/L2) -> loads
// Gen is broadcast to 16 per-group lines so each line has <=16 pollers.
__device__ __forceinline__ void grid_barrier(unsigned* bar, unsigned& epoch, int g) {
    __syncthreads();
    if (threadIdx.x == 0) {
        ++epoch;
        unsigned* root = bar;
        unsigned* gen  = bar + 64 * (1 + g);
        unsigned* grp  = bar + 64 * (17 + g);
        __builtin_amdgcn_fence(__ATOMIC_RELEASE, "agent");
        const unsigned p = __hip_atomic_fetch_add(grp, 1u, __ATOMIC_RELAXED, __HIP_MEMORY_SCOPE_AGENT);
        if (p == 15u) {
            const unsigned q = __hip_atomic_fetch_add(root, 1u, __ATOMIC_RELAXED, __HIP_MEMORY_SCOPE_AGENT);
            if (q == 15u) {
                __hip_atomic_store(root, 0u, __ATOMIC_RELAXED, __HIP_MEMORY_SCOPE_AGENT);
#pragma unroll
                for (int k = 0; k < 16; ++k)
                    __hip_atomic_store(bar + 64 * (17 + k), 0u, __ATOMIC_RELAXED, __HIP_MEMORY_SCOPE_AGENT);
                __builtin_amdgcn_fence(__ATOMIC_RELEASE, "agent");   // resets before gen
#pragma unroll
                for (int k = 0; k < 16; ++k)
                    __hip_atomic_store(bar + 64 * (1 + k), epoch, __ATOMIC_RELAXED, __HIP_MEMORY_SCOPE_AGENT);
            }
        }
        while (__hip_atomic_load(gen, __ATOMIC_RELAXED, __HIP_MEMORY_SCOPE_AGENT) < epoch)
            __builtin_amdgcn_s_sleep(2);
        __builtin_amdgcn_fence(__ATOMIC_ACQUIRE, "agent");
    }
    __syncthreads();
}

// ---------------- K3: persistent Sinkhorn ----------------
// Block b owns rows [8b,8b+8) of E and cols [8b,8b+8) of F in registers.
// j-mapping per thread: lo: j=4*tid+k, hi: j=1024+4*tid+k  -> wu/wv read as
// coalesced float4 NORMAL loads (fresh because barrier acquire fence
// invalidates L1/L2; writes are cache-bypassing relaxed atomics).
__global__ __launch_bounds__(256, 1) void k_sinkhorn(const float* __restrict__ E,
                                                     const float* __restrict__ F,
                                                     float* wu, float* wv,
                                                     unsigned* bar,
                                                     const float* __restrict__ alpha) {
    const int b = blockIdx.x, tid = threadIdx.x;
    const int lane = tid & 63, wid = tid >> 6;
    const int base = b * 8;
    const bool last = (b == NB - 1);
    const int g = b >> 4;
    __shared__ float red[4][9];

    const float norm = -8.317766166719343f;            // -log(4096)
    const float logbin = 7.624618986159398f + norm;     // log(2048) + norm
    const float ea = expf(alpha[0]);

    // register-resident fragments, j-mapped to the float4 exchange layout
    float4 elo[8], ehi[8], flo[8], fhi[8];
#pragma unroll
    for (int r = 0; r < 8; ++r) {
        const float* rowE = E + (size_t)(base + r) * SP;
        const float* rowF = F + (size_t)(base + r) * SP;
        elo[r] = *(const float4*)(rowE + 4 * tid);
        ehi[r] = *(const float4*)(rowE + 1024 + 4 * tid);
        flo[r] = *(const float4*)(rowF + 4 * tid);
        fhi[r] = *(const float4*)(rowF + 1024 + 4 * tid);
    }

    const float4* wv4 = (const float4*)wv;
    const float4* wu4 = (const float4*)wu;

    float u = 0.0f, v = 0.0f;      // potentials for row/col base+tid (tid<8)
    float ub = 0.0f, vb = 0.0f;    // dustbin potentials (block 255, tid 8)
    unsigned epoch = 0;

    for (int it = 0; it < ITERS_N; ++it) {
        // ---- phase A: S_i = sum_j E_ij wv_j -> update u, publish wu ----
        {
            const float4 wa = wv4[tid];
            const float4 wh = wv4[256 + tid];
            const float  wd = (tid == 0) ? wv[2048] : 0.0f;
            float p[8];
#pragma unroll
            for (int r = 0; r < 8; ++r) {
                p[r] = elo[r].x * wa.x + elo[r].y * wa.y + elo[r].z * wa.z + elo[r].w * wa.w
                     + ehi[r].x * wh.x + ehi[r].y * wh.y + ehi[r].z * wh.z + ehi[r].w * wh.w
                     + ea * wd;
            }
            float t = wa.x + wa.y + wa.z + wa.w + wh.x + wh.y + wh.z + wh.w + wd;
#pragma unroll
            for (int r = 0; r < 8; ++r) {
                float s = p[r];
#pragma unroll
                for (int m = 1; m < 64; m <<= 1) s += __shfl_xor(s, m, 64);
                if (lane == 0) red[wid][r] = s;
            }
#pragma unroll
            for (int m = 1; m < 64; m <<= 1) t += __shfl_xor(t, m, 64);
            if (lane == 0) red[wid][8] = t;
            __syncthreads();
            if (tid < 8) {
                const float S = red[0][tid] + red[1][tid] + red[2][tid] + red[3][tid];
                const float unew = (norm - logf(S)) / TAU_F;
                u = u + EPS_F * (unew - u);
                __hip_atomic_store(wu + base + tid, expf(u), __ATOMIC_RELAXED, __HIP_MEMORY_SCOPE_AGENT);
            }
            if (last && tid == 8) {
                const float S = ea * (red[0][8] + red[1][8] + red[2][8] + red[3][8]);
                const float unew = (logbin - logf(S)) / TAU_F;
                ub = ub + EPS_F * (unew - ub);
                __hip_atomic_store(wu + NINNER, expf(ub), __ATOMIC_RELAXED, __HIP_MEMORY_SCOPE_AGENT);
            }
        }
        grid_barrier(bar, epoch, g);
        // ---- phase B: T_j = sum_i F_ji wu_i -> update v, publish wv ----
        {
            const float4 wa = wu4[tid];
            const float4 wh = wu4[256 + tid];
            const float  wd = (tid == 0) ? wu[2048] : 0.0f;
            float p[8];
#pragma unroll
            for (int r = 0; r < 8; ++r) {
                p[r] = flo[r].x * wa.x + flo[r].y * wa.y + flo[r].z * wa.z + flo[r].w * wa.w
                     + fhi[r].x * wh.x + fhi[r].y * wh.y + fhi[r].z * wh.z + fhi[r].w * wh.w
                     + ea * wd;
            }
            float t = wa.x + wa.y + wa.z + wa.w + wh.x + wh.y + wh.z + wh.w + wd;
#pragma unroll
            for (int r = 0; r < 8; ++r) {
                float s = p[r];
#pragma unroll
                for (int m = 1; m < 64; m <<= 1) s += __shfl_xor(s, m, 64);
                if (lane == 0) red[wid][r] = s;
            }
#pragma unroll
            for (int m = 1; m < 64; m <<= 1) t += __shfl_xor(t, m, 64);
            if (lane == 0) red[wid][8] = t;
            __syncthreads();
            if (tid < 8) {
                const float T = red[0][tid] + red[1][tid] + red[2][tid] + red[3][tid];
                const float vnew = (norm - logf(T)) / TAU_F;
                v = v + EPS_F * (vnew - v);
                __hip_atomic_store(wv + base + tid, expf(v), __ATOMIC_RELAXED, __HIP_MEMORY_SCOPE_AGENT);
            }
            if (last && tid == 8) {
                const float T = ea * (red[0][8] + red[1][8] + red[2][8] + red[3][8]);
                const float vnew = (logbin - logf(T)) / TAU_F;
                vb = vb + EPS_F * (vnew - vb);
                __hip_atomic_store(wv + NINNER, expf(vb), __ATOMIC_RELAXED, __HIP_MEMORY_SCOPE_AGENT);
            }
        }
        grid_barrier(bar, epoch, g);
    }
}

// ---------------- K4: out0 = exp(Z) + row max/argmax ----------------
__global__ __launch_bounds__(256) void k_rowpass(const float* __restrict__ E,
                                                 const float* __restrict__ wu,
                                                 const float* __restrict__ wv,
                                                 float* __restrict__ out,
                                                 float* __restrict__ max0,
                                                 int* __restrict__ idx0) {
    const int i = blockIdx.x;                 // 0..2048
    const int tid = threadIdx.x;
    const int lane = tid & 63, wid = tid >> 6;
    const float wui = wu[i] * 4096.0f;        // * exp(-norm)
    const float* row = E + (size_t)i * SP;
    float best = -1.0f; int bidx = 0;
    for (int j = tid; j < NROW; j += 256) {
        const float val = row[j] * wv[j] * wui;
        out[(size_t)i * NROW + j] = val;
        if (j < NINNER && val > best) { best = val; bidx = j; }
    }
    if (i < NINNER) {
        __shared__ float sb[4]; __shared__ int si[4];
#pragma unroll
        for (int m = 1; m < 64; m <<= 1) {
            const float ob = __shfl_xor(best, m, 64);
            const int   oi = __shfl_xor(bidx, m, 64);
            if (ob > best || (ob == best && oi < bidx)) { best = ob; bidx = oi; }
        }
        if (lane == 0) { sb[wid] = best; si[wid] = bidx; }
        __syncthreads();
        if (tid == 0) {
            for (int k = 1; k < 4; ++k)
                if (sb[k] > best || (sb[k] == best && si[k] < bidx)) { best = sb[k]; bidx = si[k]; }
            max0[i] = best; idx0[i] = bidx;
        }
    }
}

// ---------------- K5: col argmax via F ----------------
__global__ __launch_bounds__(256) void k_colpass(const float* __restrict__ F,
                                                 const float* __restrict__ wu,
                                                 int* __restrict__ idx1) {
    const int j = blockIdx.x;                 // 0..2047
    const int tid = threadIdx.x;
    const int lane = tid & 63, wid = tid >> 6;
    const float* row = F + (size_t)j * SP;
    float best = -1.0f; int bidx = 0;
    for (int i = tid; i < NINNER; i += 256) {
        const float q = row[i] * wu[i];
        if (q > best) { best = q; bidx = i; }
    }
    __shared__ float sb[4]; __shared__ int si[4];
#pragma unroll
    for (int m = 1; m < 64; m <<= 1) {
        const float ob = __shfl_xor(best, m, 64);
        const int   oi = __shfl_xor(bidx, m, 64);
        if (ob > best || (ob == best && oi < bidx)) { best = ob; bidx = oi; }
    }
    if (lane == 0) { sb[wid] = best; si[wid] = bidx; }
    __syncthreads();
    if (tid == 0) {
        for (int k = 1; k < 4; ++k)
            if (sb[k] > best || (sb[k] == best && si[k] < bidx)) { best = sb[k]; bidx = si[k]; }
        idx1[j] = bidx;
    }
}

// ---------------- K6a/K6b: mutual matching ----------------
__global__ __launch_bounds__(256) void k_match0(const float* __restrict__ max0,
                                                const int* __restrict__ idx0,
                                                const int* __restrict__ idx1,
                                                float* __restrict__ ms0,
                                                int* __restrict__ vld0,
                                                float* __restrict__ out) {
    const int i = blockIdx.x * 256 + threadIdx.x;
    if (i >= NINNER) return;
    const int j = idx0[i];
    const bool mut = (idx1[j] == i);
    const float ms = mut ? max0[i] : 0.0f;
    const bool val = mut && (ms > 0.2f);
    ms0[i] = ms; vld0[i] = val ? 1 : 0;
    out[OOFF_I0 + i] = val ? (float)j : -1.0f;
    out[OOFF_S0 + i] = ms;
}
__global__ __launch_bounds__(256) void k_match1(const int* __restrict__ idx0,
                                                const int* __restrict__ idx1,
                                                const float* __restrict__ ms0,
                                                const int* __restrict__ vld0,
                                                float* __restrict__ out) {
    const int j = blockIdx.x * 256 + threadIdx.x;
    if (j >= NINNER) return;
    const int i = idx1[j];
    const bool mut = (idx0[i] == j);
    const float ms = mut ? ms0[i] : 0.0f;
    const bool val = mut && (vld0[i] != 0);
    out[OOFF_I1 + j] = val ? (float)i : -1.0f;
    out[OOFF_S1 + j] = ms;
}

// ---------------- host ----------------
extern "C" void kernel_launch(void* const* d_in, const int* in_sizes, int n_in,
                              void* d_out, int out_size, void* d_ws, size_t ws_size,
                              hipStream_t stream) {
    const float* A     = (const float*)d_in[0];   // mdesc0 (1,256,2048)
    const float* Bm    = (const float*)d_in[1];   // mdesc1 (1,256,2048)
    const float* alpha = (const float*)d_in[2];   // bin_score scalar

    float* ws = (float*)d_ws;
    float*    E    = ws + OFF_E;
    float*    F    = ws + OFF_F;
    float*    wu   = ws + OFF_WU;
    float*    wv   = ws + OFF_WV;
    unsigned* bar  = (unsigned*)(ws + OFF_BAR);
    float*    max0 = ws + OFF_MAX0;
    int*      idx0 = (int*)(ws + OFF_IDX0);
    int*      idx1 = (int*)(ws + OFF_IDX1);
    float*    ms0  = ws + OFF_MS0;
    int*      vld0 = (int*)(ws + OFF_VLD0);
    float*    out  = (float*)d_out;

    k_gemm<<<dim3(32, 32), 256, 0, stream>>>(A, Bm, E);
    k_init<<<dim3(16), 256, 0, stream>>>(E, wv, bar, alpha);
    k_transpose<<<dim3(65, 65), 256, 0, stream>>>(E, F);
    k_sinkhorn<<<dim3(NB), NT, 0, stream>>>(E, F, wu, wv, bar, alpha);
    k_rowpass<<<dim3(NROW), 256, 0, stream>>>(E, wu, wv, out, max0, idx0);
    k_colpass<<<dim3(NINNER), 256, 0, stream>>>(F, wu, idx1);
    k_match0<<<dim3(8), 256, 0, stream>>>(max0, idx0, idx1, ms0, vld0, out);
    k_match1<<<dim3(8), 256, 0, stream>>>(idx0, idx1, ms0, vld0, out);
}